// Round 5
// baseline (293.491 us; speedup 1.0000x reference)
//
#include <hip/hip_runtime.h>
#include <math.h>

// Problem constants: B=4, N=256, C=512, H=8, Dh=64
#define BB 4
#define NN 256
#define CC 512
#define HH 8
#define DH 64

typedef __attribute__((ext_vector_type(8))) short bf16x8;
typedef __attribute__((ext_vector_type(4))) float f32x4;
typedef __attribute__((ext_vector_type(2))) float f32x2;

__device__ inline unsigned short f2bf(float f) {
  unsigned u = __float_as_uint(f);
  u += 0x7FFFu + ((u >> 16) & 1u);  // round-to-nearest-even
  return (unsigned short)(u >> 16);
}
__device__ inline float bf2f(unsigned short s) {
  return __uint_as_float((unsigned)s << 16);
}

// ---------------------------------------------------------------------------
// Fused fp32 -> (hi, lo) bf16 split for all three inputs in ONE launch.
// Segments (blocks): x = 512, w_qkv = 768, w_proj = 256  -> grid 1536.
// Convert-ONCE is cheaper than in-GEMM-staging conversion (r4 post-mortem:
// staging conversion re-does the split per consuming block, ~+8 us).
// ---------------------------------------------------------------------------
__global__ __launch_bounds__(256) void cvt_hilo3(
    const float* __restrict__ in0, unsigned short* __restrict__ h0,
    unsigned short* __restrict__ l0, const float* __restrict__ in1,
    unsigned short* __restrict__ h1, unsigned short* __restrict__ l1,
    const float* __restrict__ in2, unsigned short* __restrict__ h2,
    unsigned short* __restrict__ l2) {
  int b = blockIdx.x;
  const float* in;
  unsigned short *h, *l;
  if (b < 512) {
    in = in0; h = h0; l = l0;
  } else if (b < 1280) {
    in = in1; h = h1; l = l1; b -= 512;
  } else {
    in = in2; h = h2; l = l2; b -= 1280;
  }
  int i = (b * 256 + threadIdx.x) * 4;
  float4 f = *(const float4*)(in + i);
  float fa[4] = {f.x, f.y, f.z, f.w};
  ushort4 hv, lv;
  unsigned short* hp = (unsigned short*)&hv;
  unsigned short* lp = (unsigned short*)&lv;
#pragma unroll
  for (int j = 0; j < 4; j++) {
    unsigned short hb = f2bf(fa[j]);
    hp[j] = hb;
    lp[j] = f2bf(fa[j] - bf2f(hb));
  }
  *(ushort4*)(h + i) = hv;
  *(ushort4*)(l + i) = lv;
}

// ---------------------------------------------------------------------------
// MFMA GEMM, bf16 hi/lo split (3 products): C = A * B^T (+bias).
// r3-proven structure: LDS double-buffer, ONE barrier per K-step.
// 256 thr = 4 waves; tile 64x64; wave -> 32x32 (2x2 mfma 16x16x32). BK=64.
// LDS rows padded to 72 shorts (144B): b128 frags conflict-free. 72KB LDS.
// ---------------------------------------------------------------------------
template <bool BIAS>
__global__ __launch_bounds__(256, 2) void gemm_mfma(
    const unsigned short* __restrict__ Ah, const unsigned short* __restrict__ Al,
    const unsigned short* __restrict__ Bh, const unsigned short* __restrict__ Bl,
    const float* __restrict__ bias, float* __restrict__ C, int M, int N,
    int K) {
  __shared__ unsigned short sAh[2][64][72], sAl[2][64][72];
  __shared__ unsigned short sBh[2][64][72], sBl[2][64][72];
  const int t = threadIdx.x;
  const int lane = t & 63;
  const int w = t >> 6;
  const int bm = blockIdx.y * 64;
  const int bn = blockIdx.x * 64;
  const int wr = (w >> 1) * 32;  // wave row offset in tile
  const int wc = (w & 1) * 32;   // wave col offset
  const int quad = lane >> 4;
  const int l16 = lane & 15;

  // staging: 512 slots of 8 shorts per array
  const int r0 = t >> 3;       // 0..31
  const int r1 = r0 + 32;      // 32..63
  const int c8 = (t & 7) * 8;  // 0..56

  const size_t a0 = (size_t)(bm + r0) * K + c8;
  const size_t a1 = (size_t)(bm + r1) * K + c8;
  const size_t b0 = (size_t)(bn + r0) * K + c8;
  const size_t b1 = (size_t)(bn + r1) * K + c8;

  f32x4 acc[2][2];
#pragma unroll
  for (int i = 0; i < 2; i++)
#pragma unroll
    for (int j = 0; j < 2; j++) {
      acc[i][j][0] = 0.f;
      acc[i][j][1] = 0.f;
      acc[i][j][2] = 0.f;
      acc[i][j][3] = 0.f;
    }

  uint4 pa0, pa1, pa2, pa3, pb0, pb1, pb2, pb3;
#define GLOADS(K0)                       \
  pa0 = *(const uint4*)(Ah + a0 + (K0)); \
  pa1 = *(const uint4*)(Ah + a1 + (K0)); \
  pa2 = *(const uint4*)(Al + a0 + (K0)); \
  pa3 = *(const uint4*)(Al + a1 + (K0)); \
  pb0 = *(const uint4*)(Bh + b0 + (K0)); \
  pb1 = *(const uint4*)(Bh + b1 + (K0)); \
  pb2 = *(const uint4*)(Bl + b0 + (K0)); \
  pb3 = *(const uint4*)(Bl + b1 + (K0));

#define STORE(P)                  \
  *(uint4*)&sAh[P][r0][c8] = pa0; \
  *(uint4*)&sAh[P][r1][c8] = pa1; \
  *(uint4*)&sAl[P][r0][c8] = pa2; \
  *(uint4*)&sAl[P][r1][c8] = pa3; \
  *(uint4*)&sBh[P][r0][c8] = pb0; \
  *(uint4*)&sBh[P][r1][c8] = pb1; \
  *(uint4*)&sBl[P][r0][c8] = pb2; \
  *(uint4*)&sBl[P][r1][c8] = pb3;

  GLOADS(0)
  STORE(0)
  __syncthreads();
  GLOADS(64)

  int p = 0;
  for (int k0 = 0; k0 < K; k0 += 64) {
#pragma unroll
    for (int kk = 0; kk < 2; kk++) {
      const int kc = kk * 32 + quad * 8;
      bf16x8 ah[2], al[2], bh[2], bl[2];
#pragma unroll
      for (int i = 0; i < 2; i++) {
        ah[i] = *(const bf16x8*)&sAh[p][wr + i * 16 + l16][kc];
        al[i] = *(const bf16x8*)&sAl[p][wr + i * 16 + l16][kc];
        bh[i] = *(const bf16x8*)&sBh[p][wc + i * 16 + l16][kc];
        bl[i] = *(const bf16x8*)&sBl[p][wc + i * 16 + l16][kc];
      }
#pragma unroll
      for (int i = 0; i < 2; i++)
#pragma unroll
        for (int j = 0; j < 2; j++) {
          acc[i][j] = __builtin_amdgcn_mfma_f32_16x16x32_bf16(
              ah[i], bh[j], acc[i][j], 0, 0, 0);
          acc[i][j] = __builtin_amdgcn_mfma_f32_16x16x32_bf16(
              ah[i], bl[j], acc[i][j], 0, 0, 0);
          acc[i][j] = __builtin_amdgcn_mfma_f32_16x16x32_bf16(
              al[i], bh[j], acc[i][j], 0, 0, 0);
        }
    }
    if (k0 + 64 < K) {
      STORE(p ^ 1)
      if (k0 + 128 < K) {
        GLOADS(k0 + 128)
      }
    }
    __syncthreads();
    p ^= 1;
  }
#undef GLOADS
#undef STORE

  // epilogue: C/D layout col=lane&15, row=quad*4+reg (verified m89/m91)
#pragma unroll
  for (int i = 0; i < 2; i++)
#pragma unroll
    for (int j = 0; j < 2; j++) {
      int n = bn + wc + j * 16 + l16;
      float bv = BIAS ? bias[n] : 0.f;
#pragma unroll
      for (int r = 0; r < 4; r++) {
        int m = bm + wr + i * 16 + quad * 4 + r;
        C[(size_t)m * N + n] = acc[i][j][r] + bv;
      }
    }
}

// ---------------------------------------------------------------------------
// Fused Fourier attention v6: key-split (2-way) + NO V TILE IN LDS.
// Grid (x = b*8+h [32], y = qc*2+kc [32]) = 1024 blocks; 512 thr = 8 waves.
// Each block: 16 queries x 128 keys (2 tiles of 64), writes PARTIAL fp32
// numerator + denominator; combine_norm folds them for gemm2.
// Occupancy: LDS = Kt 17.4K + Qs 4K + P 4.6K + Red 4K ~= 30KB ->
// 4 blocks/CU (32 waves/CU, the cap) with __launch_bounds__(512,8)
// (vs r3: 48KB, 2 blocks, 16 waves -> latency-bound at 29% occupancy).
// V is read straight from global (L2-resident, XCD-local: dispatch id%8 = h)
// into regs, issued just before the P-barrier so latency hides under it.
// Score math identical to r3 (collision-safe eps ordering).
// ---------------------------------------------------------------------------
__global__ __launch_bounds__(512, 8) void fourier_attn(
    const float* __restrict__ qkv, const float* __restrict__ paramR,
    float* __restrict__ num0, float* __restrict__ num1,
    float* __restrict__ den0, float* __restrict__ den1) {
  __shared__ float Kt[64][68];            // K tile, row-major, padded
  __shared__ float Qs[16][64];            // staged queries (broadcast reads)
  __shared__ unsigned short Pah[16][72];  // a4 hi (bf16), padded 144B rows
  __shared__ unsigned short Pal[16][72];  // a4 lo
  __shared__ f32x4 Red[4][64];            // cross-wave partial sums

  const int t = threadIdx.x;
  const int lane = t & 63;
  const int wv = t >> 6;  // 0..7
  const int quad = lane >> 4;
  const int l16 = lane & 15;
  const int h = blockIdx.x & 7;
  const int b = blockIdx.x >> 3;
  const int qc = blockIdx.y >> 1;
  const int kc = blockIdx.y & 1;  // key half: tiles kc*2 .. kc*2+1
  const float R = paramR[0];
  const float cR = R * 0.15915494309189535f;  // R / (2*pi)

  const float* base = qkv + (size_t)b * NN * (3 * CC) + h * DH;

  if (t < 256) {
    int r = t >> 4;
    int c4 = (t & 15) << 2;
    *(float4*)&Qs[r][c4] =
        *(const float4*)(base + (size_t)(qc * 16 + r) * (3 * CC) + c4);
  }

  const int qi0 = wv * 2, qi1 = wv * 2 + 1;
  float Sp[2] = {0.f, 0.f};
  f32x4 oacc;
  oacc[0] = 0.f; oacc[1] = 0.f; oacc[2] = 0.f; oacc[3] = 0.f;

  // AV-phase role: dims chunk nc, key-half-within-tile g2
  const int nc = wv & 3;
  const int g2 = wv >> 2;
  const int kb = g2 * 32 + quad * 8;
  const int vcol = nc * 16 + l16;

  // K-tile prefetch regs (2 float4)
  float4 pk[2];
#define LOADK(JT)                                                         \
  _Pragma("unroll") for (int u0 = 0; u0 < 2; u0++) {                      \
    int u = t + 512 * u0;                                                 \
    int r_ = u >> 4;                                                      \
    int c4_ = (u & 15) << 2;                                              \
    pk[u0] =                                                              \
        *(const float4*)(base + (size_t)((JT) * 64 + r_) * (3 * CC) + CC + \
                         c4_);                                            \
  }

  LOADK(kc * 2)

  const f32x2 eps2 = {1e-30f, 1e-30f};
  const f32x2 cR2 = {cR, cR};

  for (int jj = 0; jj < 2; jj++) {
    const int jt = kc * 2 + jj;
    __syncthreads();  // B1: prev tile's score reads of Kt / AV reads of P done
#pragma unroll
    for (int u0 = 0; u0 < 2; u0++) {
      int u = t + 512 * u0;
      int r = u >> 4;          // key row
      int c4 = (u & 15) << 2;  // dim
      *(float4*)&Kt[r][c4] = pk[u0];
    }
    __syncthreads();  // B2: K tile (and Qs on jj=0) ready
    if (jj == 0) {
      LOADK(kc * 2 + 1)  // in flight across score below
    }

    // ---- score phase: lane = key, packed f32x2 math
    f32x2 nmA0 = {1.f, 1.f}, nmB0 = {1.f, 1.f};
    f32x2 nmA1 = {1.f, 1.f}, nmB1 = {1.f, 1.f};
    f32x2 dnA0 = {1.f, 1.f}, dnB0 = {1.f, 1.f};
    f32x2 dnA1 = {1.f, 1.f}, dnB1 = {1.f, 1.f};
#pragma unroll
    for (int d4 = 0; d4 < 16; d4++) {
      float4 k4 = *(const float4*)&Kt[lane][4 * d4];
      float4 qa = *(const float4*)&Qs[qi0][4 * d4];
      float4 qb = *(const float4*)&Qs[qi1][4 * d4];
      f32x2 kA = {k4.x, k4.y};
      f32x2 kB = {k4.z, k4.w};
      // (q - k) FIRST, then + eps: collision-safe (r2 NaN post-mortem)
      f32x2 dA0 = ((f32x2){qa.x, qa.y} - kA) + eps2;
      f32x2 dB0 = ((f32x2){qa.z, qa.w} - kB) + eps2;
      f32x2 dA1 = ((f32x2){qb.x, qb.y} - kA) + eps2;
      f32x2 dB1 = ((f32x2){qb.z, qb.w} - kB) + eps2;
      f32x2 gA0 = cR2 * dA0, gB0 = cR2 * dB0;
      f32x2 gA1 = cR2 * dA1, gB1 = cR2 * dB1;
      f32x2 sA0, sB0, sA1, sB1;
      sA0.x = __builtin_amdgcn_sinf(gA0.x);
      sA0.y = __builtin_amdgcn_sinf(gA0.y);
      sB0.x = __builtin_amdgcn_sinf(gB0.x);
      sB0.y = __builtin_amdgcn_sinf(gB0.y);
      sA1.x = __builtin_amdgcn_sinf(gA1.x);
      sA1.y = __builtin_amdgcn_sinf(gA1.y);
      sB1.x = __builtin_amdgcn_sinf(gB1.x);
      sB1.y = __builtin_amdgcn_sinf(gB1.y);
      nmA0 *= sA0;
      nmB0 *= sB0;
      nmA1 *= sA1;
      nmB1 *= sB1;
      dnA0 *= dA0;
      dnB0 *= dB0;
      dnA1 *= dA1;
      dnB1 *= dB1;
    }

    // ---- V prefetch from global (L2-hot; latency hides under P-write + B3)
    float vf[8];
#pragma unroll
    for (int j = 0; j < 8; j++) {
      vf[j] = base[(size_t)(jt * 64 + kb + j) * (3 * CC) + 2 * CC + vcol];
    }

    {
      f32x2 n0 = nmA0 * nmB0, d0 = dnA0 * dnB0;
      f32x2 n1 = nmA1 * nmB1, d1 = dnA1 * dnB1;
      float sc0 = (n0.x * n0.y) / (d0.x * d0.y);
      float sc1 = (n1.x * n1.y) / (d1.x * d1.y);
      float t0 = sc0 * sc0, t1 = sc1 * sc1;
      float a40 = t0 * t0, a41 = t1 * t1;
      Sp[0] += a40;
      Sp[1] += a41;
      unsigned short h0 = f2bf(a40), h1 = f2bf(a41);
      Pah[qi0][lane] = h0;
      Pal[qi0][lane] = f2bf(a40 - bf2f(h0));
      Pah[qi1][lane] = h1;
      Pal[qi1][lane] = f2bf(a41 - bf2f(h1));
    }
    __syncthreads();  // B3: P tile complete

    // ---- AV phase: one 16x16x32 MFMA triple per wave
    {
      bf16x8 pah = *(const bf16x8*)&Pah[l16][kb];
      bf16x8 pal = *(const bf16x8*)&Pal[l16][kb];
      bf16x8 vh, vl;
#pragma unroll
      for (int j = 0; j < 8; j++) {
        float f = vf[j];
        unsigned short hb = f2bf(f);
        vh[j] = (short)hb;
        vl[j] = (short)f2bf(f - bf2f(hb));
      }
      __builtin_amdgcn_s_setprio(1);
      oacc = __builtin_amdgcn_mfma_f32_16x16x32_bf16(pah, vh, oacc, 0, 0, 0);
      oacc = __builtin_amdgcn_mfma_f32_16x16x32_bf16(pah, vl, oacc, 0, 0, 0);
      oacc = __builtin_amdgcn_mfma_f32_16x16x32_bf16(pal, vh, oacc, 0, 0, 0);
      __builtin_amdgcn_s_setprio(0);
    }
  }
#undef LOADK

  // ---- finalize: write partial den (per query) + partial num (fp32)
  float* nump = kc ? num1 : num0;
  float* denp = kc ? den1 : den0;
#pragma unroll
  for (int q = 0; q < 2; q++) {
    float s = Sp[q];
#pragma unroll
    for (int off = 32; off > 0; off >>= 1) s += __shfl_xor(s, off, 64);
    if (lane == 0) {
      int m = b * NN + qc * 16 + qi0 + q;
      denp[(size_t)m * HH + h] = s;
    }
  }
  if (wv >= 4) Red[wv - 4][lane] = oacc;
  __syncthreads();
  if (wv < 4) {
    f32x4 part = Red[wv][lane];
#pragma unroll
    for (int r = 0; r < 4; r++) {
      int q = quad * 4 + r;
      int m = b * NN + qc * 16 + q;
      nump[(size_t)m * CC + h * DH + nc * 16 + l16] = oacc[r] + part[r];
    }
  }
}

// ---------------------------------------------------------------------------
// combine_norm: aoh/aol = hi/lo bf16 of (num0+num1)/(den0+den1+1e-6).
// 524288 elems, 4/thread -> 512 blocks x 256. ~6 MB traffic ~ 1.5 us.
// ---------------------------------------------------------------------------
__global__ __launch_bounds__(256) void combine_norm(
    const float* __restrict__ num0, const float* __restrict__ num1,
    const float* __restrict__ den0, const float* __restrict__ den1,
    unsigned short* __restrict__ aoh, unsigned short* __restrict__ aol) {
  int e = (blockIdx.x * 256 + threadIdx.x) * 4;
  int m = e >> 9;          // row (b*N+n)
  int hd = (e >> 6) & 7;   // head
  float den = den0[(size_t)m * HH + hd] + den1[(size_t)m * HH + hd] + 1e-6f;
  float4 n0 = *(const float4*)(num0 + e);
  float4 n1 = *(const float4*)(num1 + e);
  float o[4] = {(n0.x + n1.x) / den, (n0.y + n1.y) / den,
                (n0.z + n1.z) / den, (n0.w + n1.w) / den};
  ushort4 hv, lv;
  unsigned short* hp = (unsigned short*)&hv;
  unsigned short* lp = (unsigned short*)&lv;
#pragma unroll
  for (int j = 0; j < 4; j++) {
    unsigned short hb = f2bf(o[j]);
    hp[j] = hb;
    lp[j] = f2bf(o[j] - bf2f(hb));
  }
  *(ushort4*)(aoh + e) = hv;
  *(ushort4*)(aol + e) = lv;
}

// ---------------------------------------------------------------------------
extern "C" void kernel_launch(void* const* d_in, const int* in_sizes, int n_in,
                              void* d_out, int out_size, void* d_ws,
                              size_t ws_size, hipStream_t stream) {
  const float* x = (const float*)d_in[0];       // (B,N,C)
  const float* w_qkv = (const float*)d_in[1];   // (3C, C)
  const float* w_proj = (const float*)d_in[2];  // (C, C)
  const float* b_proj = (const float*)d_in[3];  // (C,)
  const float* paramR = (const float*)d_in[4];  // (1,)
  float* outp = (float*)d_out;                  // (B,N,C)

  const int nX = BB * NN * CC;  // 524288
  const int nWq = 3 * CC * CC;  // 786432
  const int nWp = CC * CC;      // 262144

  // ws layout: bf16 buffers first (8.4 MB, 16B-aligned), then fp32
  unsigned short* xh = (unsigned short*)d_ws;
  unsigned short* xl = xh + nX;
  unsigned short* wqh = xl + nX;
  unsigned short* wql = wqh + nWq;
  unsigned short* wph = wql + nWq;
  unsigned short* wpl = wph + nWp;
  unsigned short* aoh = wpl + nWp;
  unsigned short* aol = aoh + nX;
  float* qkv_ws = (float*)(aol + nX);   // 1024*1536 fp32
  float* num0 = qkv_ws + 1024 * 1536;   // 1024*512
  float* num1 = num0 + nX;              // 1024*512
  float* den0 = num1 + nX;              // 1024*8
  float* den1 = den0 + 1024 * HH;       // 1024*8

  // 1) hi/lo conversions (single fused launch)
  cvt_hilo3<<<1536, 256, 0, stream>>>(x, xh, xl, w_qkv, wqh, wql, w_proj, wph,
                                      wpl);

  // 2) qkv = x @ w_qkv^T : M=1024, N=1536, K=512 (384 blocks)
  gemm_mfma<false><<<dim3(3 * CC / 64, BB * NN / 64), 256, 0, stream>>>(
      xh, xl, wqh, wql, nullptr, qkv_ws, BB * NN, 3 * CC, CC);

  // 3) fused fourier attention, key-split 2-way -> partial num/den
  fourier_attn<<<dim3(HH * BB, (NN / 16) * 2), 512, 0, stream>>>(
      qkv_ws, paramR, num0, num1, den0, den1);

  // 4) combine + normalize -> hi/lo bf16 attention output
  combine_norm<<<nX / 1024, 256, 0, stream>>>(num0, num1, den0, den1, aoh,
                                              aol);

  // 5) out = attn @ w_proj^T + b_proj : M=1024, N=512, K=512 (128 blocks)
  gemm_mfma<true><<<dim3(CC / 64, BB * NN / 64), 256, 0, stream>>>(
      aoh, aol, wph, wpl, b_proj, outp, BB * NN, CC, CC);
}

// Round 6
// 230.627 us; speedup vs baseline: 1.2726x; 1.2726x over previous
//
#include <hip/hip_runtime.h>
#include <math.h>

// Problem constants: B=4, N=256, C=512, H=8, Dh=64
#define BB 4
#define NN 256
#define CC 512
#define HH 8
#define DH 64

typedef __attribute__((ext_vector_type(8))) short bf16x8;
typedef __attribute__((ext_vector_type(4))) float f32x4;
typedef __attribute__((ext_vector_type(2))) float f32x2;

__device__ inline unsigned short f2bf(float f) {
  unsigned u = __float_as_uint(f);
  u += 0x7FFFu + ((u >> 16) & 1u);  // round-to-nearest-even
  return (unsigned short)(u >> 16);
}
__device__ inline float bf2f(unsigned short s) {
  return __uint_as_float((unsigned)s << 16);
}

// ---------------------------------------------------------------------------
// Fused fp32 -> (hi, lo) bf16 split for all three inputs in ONE launch.
// Segments (blocks): x = 512, w_qkv = 768, w_proj = 256  -> grid 1536.
// ---------------------------------------------------------------------------
__global__ __launch_bounds__(256) void cvt_hilo3(
    const float* __restrict__ in0, unsigned short* __restrict__ h0,
    unsigned short* __restrict__ l0, const float* __restrict__ in1,
    unsigned short* __restrict__ h1, unsigned short* __restrict__ l1,
    const float* __restrict__ in2, unsigned short* __restrict__ h2,
    unsigned short* __restrict__ l2) {
  int b = blockIdx.x;
  const float* in;
  unsigned short *h, *l;
  if (b < 512) {
    in = in0; h = h0; l = l0;
  } else if (b < 1280) {
    in = in1; h = h1; l = l1; b -= 512;
  } else {
    in = in2; h = h2; l = l2; b -= 1280;
  }
  int i = (b * 256 + threadIdx.x) * 4;
  float4 f = *(const float4*)(in + i);
  float fa[4] = {f.x, f.y, f.z, f.w};
  ushort4 hv, lv;
  unsigned short* hp = (unsigned short*)&hv;
  unsigned short* lp = (unsigned short*)&lv;
#pragma unroll
  for (int j = 0; j < 4; j++) {
    unsigned short hb = f2bf(fa[j]);
    hp[j] = hb;
    lp[j] = f2bf(fa[j] - bf2f(hb));
  }
  *(ushort4*)(h + i) = hv;
  *(ushort4*)(l + i) = lv;
}

// ---------------------------------------------------------------------------
// MFMA GEMM, bf16 hi/lo split (3 products): C = A * B^T (+bias).
// r3-proven structure: LDS double-buffer, ONE barrier per K-step.
// 256 thr = 4 waves; tile 64x64; wave -> 32x32 (2x2 mfma 16x16x32). BK=64.
// LDS rows padded to 72 shorts (144B): b128 frags conflict-free. 72KB LDS.
// ---------------------------------------------------------------------------
template <bool BIAS>
__global__ __launch_bounds__(256, 2) void gemm_mfma(
    const unsigned short* __restrict__ Ah, const unsigned short* __restrict__ Al,
    const unsigned short* __restrict__ Bh, const unsigned short* __restrict__ Bl,
    const float* __restrict__ bias, float* __restrict__ C, int M, int N,
    int K) {
  __shared__ unsigned short sAh[2][64][72], sAl[2][64][72];
  __shared__ unsigned short sBh[2][64][72], sBl[2][64][72];
  const int t = threadIdx.x;
  const int lane = t & 63;
  const int w = t >> 6;
  const int bm = blockIdx.y * 64;
  const int bn = blockIdx.x * 64;
  const int wr = (w >> 1) * 32;  // wave row offset in tile
  const int wc = (w & 1) * 32;   // wave col offset
  const int quad = lane >> 4;
  const int l16 = lane & 15;

  // staging: 512 slots of 8 shorts per array
  const int r0 = t >> 3;       // 0..31
  const int r1 = r0 + 32;      // 32..63
  const int c8 = (t & 7) * 8;  // 0..56

  const size_t a0 = (size_t)(bm + r0) * K + c8;
  const size_t a1 = (size_t)(bm + r1) * K + c8;
  const size_t b0 = (size_t)(bn + r0) * K + c8;
  const size_t b1 = (size_t)(bn + r1) * K + c8;

  f32x4 acc[2][2];
#pragma unroll
  for (int i = 0; i < 2; i++)
#pragma unroll
    for (int j = 0; j < 2; j++) {
      acc[i][j][0] = 0.f;
      acc[i][j][1] = 0.f;
      acc[i][j][2] = 0.f;
      acc[i][j][3] = 0.f;
    }

  uint4 pa0, pa1, pa2, pa3, pb0, pb1, pb2, pb3;
#define GLOADS(K0)                       \
  pa0 = *(const uint4*)(Ah + a0 + (K0)); \
  pa1 = *(const uint4*)(Ah + a1 + (K0)); \
  pa2 = *(const uint4*)(Al + a0 + (K0)); \
  pa3 = *(const uint4*)(Al + a1 + (K0)); \
  pb0 = *(const uint4*)(Bh + b0 + (K0)); \
  pb1 = *(const uint4*)(Bh + b1 + (K0)); \
  pb2 = *(const uint4*)(Bl + b0 + (K0)); \
  pb3 = *(const uint4*)(Bl + b1 + (K0));

#define STORE(P)                  \
  *(uint4*)&sAh[P][r0][c8] = pa0; \
  *(uint4*)&sAh[P][r1][c8] = pa1; \
  *(uint4*)&sAl[P][r0][c8] = pa2; \
  *(uint4*)&sAl[P][r1][c8] = pa3; \
  *(uint4*)&sBh[P][r0][c8] = pb0; \
  *(uint4*)&sBh[P][r1][c8] = pb1; \
  *(uint4*)&sBl[P][r0][c8] = pb2; \
  *(uint4*)&sBl[P][r1][c8] = pb3;

  GLOADS(0)
  STORE(0)
  __syncthreads();
  GLOADS(64)

  int p = 0;
  for (int k0 = 0; k0 < K; k0 += 64) {
#pragma unroll
    for (int kk = 0; kk < 2; kk++) {
      const int kc = kk * 32 + quad * 8;
      bf16x8 ah[2], al[2], bh[2], bl[2];
#pragma unroll
      for (int i = 0; i < 2; i++) {
        ah[i] = *(const bf16x8*)&sAh[p][wr + i * 16 + l16][kc];
        al[i] = *(const bf16x8*)&sAl[p][wr + i * 16 + l16][kc];
        bh[i] = *(const bf16x8*)&sBh[p][wc + i * 16 + l16][kc];
        bl[i] = *(const bf16x8*)&sBl[p][wc + i * 16 + l16][kc];
      }
#pragma unroll
      for (int i = 0; i < 2; i++)
#pragma unroll
        for (int j = 0; j < 2; j++) {
          acc[i][j] = __builtin_amdgcn_mfma_f32_16x16x32_bf16(
              ah[i], bh[j], acc[i][j], 0, 0, 0);
          acc[i][j] = __builtin_amdgcn_mfma_f32_16x16x32_bf16(
              ah[i], bl[j], acc[i][j], 0, 0, 0);
          acc[i][j] = __builtin_amdgcn_mfma_f32_16x16x32_bf16(
              al[i], bh[j], acc[i][j], 0, 0, 0);
        }
    }
    if (k0 + 64 < K) {
      STORE(p ^ 1)
      if (k0 + 128 < K) {
        GLOADS(k0 + 128)
      }
    }
    __syncthreads();
    p ^= 1;
  }
#undef GLOADS
#undef STORE

  // epilogue: C/D layout col=lane&15, row=quad*4+reg (verified m89/m91)
#pragma unroll
  for (int i = 0; i < 2; i++)
#pragma unroll
    for (int j = 0; j < 2; j++) {
      int n = bn + wc + j * 16 + l16;
      float bv = BIAS ? bias[n] : 0.f;
#pragma unroll
      for (int r = 0; r < 4; r++) {
        int m = bm + wr + i * 16 + quad * 4 + r;
        C[(size_t)m * N + n] = acc[i][j][r] + bv;
      }
    }
}

// ---------------------------------------------------------------------------
// Fused Fourier attention v7 = v6 with the SPILL FIXED.
// r5 post-mortem: __launch_bounds__(512, 8) capped VGPRs at 64 -> compiler
// spilled the hot-loop state to scratch (global!): WRITE_SIZE 473MB vs 6MB
// real output, FETCH 249MB, kernel 5x slower. (512, 6) gives ~84 VGPRs
// (kernel needs ~64-80), zero spill, 3 blocks/CU = 24 waves/CU — still 1.5x
// the r3 occupancy that was the point of the key-split.
// Structure: grid (x = b*8+h [32], y = qc*2+kc [32]) = 1024 blocks; 8 waves.
// Each block: 16 queries x 128 keys, partial fp32 num/den; no V tile in LDS
// (V read from global/L2, XCD-local since dispatch id%8 = h).
// ---------------------------------------------------------------------------
__global__ __launch_bounds__(512, 6) void fourier_attn(
    const float* __restrict__ qkv, const float* __restrict__ paramR,
    float* __restrict__ num0, float* __restrict__ num1,
    float* __restrict__ den0, float* __restrict__ den1) {
  __shared__ float Kt[64][68];            // K tile, row-major, padded
  __shared__ float Qs[16][64];            // staged queries (broadcast reads)
  __shared__ unsigned short Pah[16][72];  // a4 hi (bf16), padded 144B rows
  __shared__ unsigned short Pal[16][72];  // a4 lo
  __shared__ f32x4 Red[4][64];            // cross-wave partial sums

  const int t = threadIdx.x;
  const int lane = t & 63;
  const int wv = t >> 6;  // 0..7
  const int quad = lane >> 4;
  const int l16 = lane & 15;
  const int h = blockIdx.x & 7;
  const int b = blockIdx.x >> 3;
  const int qc = blockIdx.y >> 1;
  const int kc = blockIdx.y & 1;  // key half: tiles kc*2 .. kc*2+1
  const float R = paramR[0];
  const float cR = R * 0.15915494309189535f;  // R / (2*pi)

  const float* base = qkv + (size_t)b * NN * (3 * CC) + h * DH;

  if (t < 256) {
    int r = t >> 4;
    int c4 = (t & 15) << 2;
    *(float4*)&Qs[r][c4] =
        *(const float4*)(base + (size_t)(qc * 16 + r) * (3 * CC) + c4);
  }

  const int qi0 = wv * 2, qi1 = wv * 2 + 1;
  float Sp[2] = {0.f, 0.f};
  f32x4 oacc;
  oacc[0] = 0.f; oacc[1] = 0.f; oacc[2] = 0.f; oacc[3] = 0.f;

  // AV-phase role: dims chunk nc, key-half-within-tile g2
  const int nc = wv & 3;
  const int g2 = wv >> 2;
  const int kb = g2 * 32 + quad * 8;
  const int vcol = nc * 16 + l16;

  // K-tile prefetch regs (2 float4)
  float4 pk[2];
#define LOADK(JT)                                                          \
  _Pragma("unroll") for (int u0 = 0; u0 < 2; u0++) {                       \
    int u = t + 512 * u0;                                                  \
    int r_ = u >> 4;                                                       \
    int c4_ = (u & 15) << 2;                                               \
    pk[u0] =                                                               \
        *(const float4*)(base + (size_t)((JT) * 64 + r_) * (3 * CC) + CC + \
                         c4_);                                             \
  }

  LOADK(kc * 2)

  const f32x2 eps2 = {1e-30f, 1e-30f};
  const f32x2 cR2 = {cR, cR};

  for (int jj = 0; jj < 2; jj++) {
    const int jt = kc * 2 + jj;
    __syncthreads();  // B1: prev tile's score reads of Kt / AV reads of P done
#pragma unroll
    for (int u0 = 0; u0 < 2; u0++) {
      int u = t + 512 * u0;
      int r = u >> 4;          // key row
      int c4 = (u & 15) << 2;  // dim
      *(float4*)&Kt[r][c4] = pk[u0];
    }
    __syncthreads();  // B2: K tile (and Qs on jj=0) ready
    if (jj == 0) {
      LOADK(kc * 2 + 1)  // in flight across score below
    }

    // ---- score phase: lane = key, packed f32x2 math
    f32x2 nmA0 = {1.f, 1.f}, nmB0 = {1.f, 1.f};
    f32x2 nmA1 = {1.f, 1.f}, nmB1 = {1.f, 1.f};
    f32x2 dnA0 = {1.f, 1.f}, dnB0 = {1.f, 1.f};
    f32x2 dnA1 = {1.f, 1.f}, dnB1 = {1.f, 1.f};
#pragma unroll
    for (int d4 = 0; d4 < 16; d4++) {
      float4 k4 = *(const float4*)&Kt[lane][4 * d4];
      float4 qa = *(const float4*)&Qs[qi0][4 * d4];
      float4 qb = *(const float4*)&Qs[qi1][4 * d4];
      f32x2 kA = {k4.x, k4.y};
      f32x2 kB = {k4.z, k4.w};
      // (q - k) FIRST, then + eps: collision-safe (r2 NaN post-mortem)
      f32x2 dA0 = ((f32x2){qa.x, qa.y} - kA) + eps2;
      f32x2 dB0 = ((f32x2){qa.z, qa.w} - kB) + eps2;
      f32x2 dA1 = ((f32x2){qb.x, qb.y} - kA) + eps2;
      f32x2 dB1 = ((f32x2){qb.z, qb.w} - kB) + eps2;
      f32x2 gA0 = cR2 * dA0, gB0 = cR2 * dB0;
      f32x2 gA1 = cR2 * dA1, gB1 = cR2 * dB1;
      f32x2 sA0, sB0, sA1, sB1;
      sA0.x = __builtin_amdgcn_sinf(gA0.x);
      sA0.y = __builtin_amdgcn_sinf(gA0.y);
      sB0.x = __builtin_amdgcn_sinf(gB0.x);
      sB0.y = __builtin_amdgcn_sinf(gB0.y);
      sA1.x = __builtin_amdgcn_sinf(gA1.x);
      sA1.y = __builtin_amdgcn_sinf(gA1.y);
      sB1.x = __builtin_amdgcn_sinf(gB1.x);
      sB1.y = __builtin_amdgcn_sinf(gB1.y);
      nmA0 *= sA0;
      nmB0 *= sB0;
      nmA1 *= sA1;
      nmB1 *= sB1;
      dnA0 *= dA0;
      dnB0 *= dB0;
      dnA1 *= dA1;
      dnB1 *= dB1;
    }

    // ---- V prefetch from global (L2-hot; latency hides under P-write + B3)
    float vf[8];
#pragma unroll
    for (int j = 0; j < 8; j++) {
      vf[j] = base[(size_t)(jt * 64 + kb + j) * (3 * CC) + 2 * CC + vcol];
    }

    {
      f32x2 n0 = nmA0 * nmB0, d0 = dnA0 * dnB0;
      f32x2 n1 = nmA1 * nmB1, d1 = dnA1 * dnB1;
      float sc0 = (n0.x * n0.y) / (d0.x * d0.y);
      float sc1 = (n1.x * n1.y) / (d1.x * d1.y);
      float t0 = sc0 * sc0, t1 = sc1 * sc1;
      float a40 = t0 * t0, a41 = t1 * t1;
      Sp[0] += a40;
      Sp[1] += a41;
      unsigned short h0 = f2bf(a40), h1 = f2bf(a41);
      Pah[qi0][lane] = h0;
      Pal[qi0][lane] = f2bf(a40 - bf2f(h0));
      Pah[qi1][lane] = h1;
      Pal[qi1][lane] = f2bf(a41 - bf2f(h1));
    }
    __syncthreads();  // B3: P tile complete

    // ---- AV phase: one 16x16x32 MFMA triple per wave
    {
      bf16x8 pah = *(const bf16x8*)&Pah[l16][kb];
      bf16x8 pal = *(const bf16x8*)&Pal[l16][kb];
      bf16x8 vh, vl;
#pragma unroll
      for (int j = 0; j < 8; j++) {
        float f = vf[j];
        unsigned short hb = f2bf(f);
        vh[j] = (short)hb;
        vl[j] = (short)f2bf(f - bf2f(hb));
      }
      __builtin_amdgcn_s_setprio(1);
      oacc = __builtin_amdgcn_mfma_f32_16x16x32_bf16(pah, vh, oacc, 0, 0, 0);
      oacc = __builtin_amdgcn_mfma_f32_16x16x32_bf16(pah, vl, oacc, 0, 0, 0);
      oacc = __builtin_amdgcn_mfma_f32_16x16x32_bf16(pal, vh, oacc, 0, 0, 0);
      __builtin_amdgcn_s_setprio(0);
    }
  }
#undef LOADK

  // ---- finalize: write partial den (per query) + partial num (fp32)
  float* nump = kc ? num1 : num0;
  float* denp = kc ? den1 : den0;
#pragma unroll
  for (int q = 0; q < 2; q++) {
    float s = Sp[q];
#pragma unroll
    for (int off = 32; off > 0; off >>= 1) s += __shfl_xor(s, off, 64);
    if (lane == 0) {
      int m = b * NN + qc * 16 + qi0 + q;
      denp[(size_t)m * HH + h] = s;
    }
  }
  if (wv >= 4) Red[wv - 4][lane] = oacc;
  __syncthreads();
  if (wv < 4) {
    f32x4 part = Red[wv][lane];
#pragma unroll
    for (int r = 0; r < 4; r++) {
      int q = quad * 4 + r;
      int m = b * NN + qc * 16 + q;
      nump[(size_t)m * CC + h * DH + nc * 16 + l16] = oacc[r] + part[r];
    }
  }
}

// ---------------------------------------------------------------------------
// combine_norm: aoh/aol = hi/lo bf16 of (num0+num1)/(den0+den1+1e-6).
// 524288 elems, 4/thread -> 512 blocks x 256. ~6 MB traffic ~ 1.5 us.
// ---------------------------------------------------------------------------
__global__ __launch_bounds__(256) void combine_norm(
    const float* __restrict__ num0, const float* __restrict__ num1,
    const float* __restrict__ den0, const float* __restrict__ den1,
    unsigned short* __restrict__ aoh, unsigned short* __restrict__ aol) {
  int e = (blockIdx.x * 256 + threadIdx.x) * 4;
  int m = e >> 9;          // row (b*N+n)
  int hd = (e >> 6) & 7;   // head
  float den = den0[(size_t)m * HH + hd] + den1[(size_t)m * HH + hd] + 1e-6f;
  float4 n0 = *(const float4*)(num0 + e);
  float4 n1 = *(const float4*)(num1 + e);
  float o[4] = {(n0.x + n1.x) / den, (n0.y + n1.y) / den,
                (n0.z + n1.z) / den, (n0.w + n1.w) / den};
  ushort4 hv, lv;
  unsigned short* hp = (unsigned short*)&hv;
  unsigned short* lp = (unsigned short*)&lv;
#pragma unroll
  for (int j = 0; j < 4; j++) {
    unsigned short hb = f2bf(o[j]);
    hp[j] = hb;
    lp[j] = f2bf(o[j] - bf2f(hb));
  }
  *(ushort4*)(aoh + e) = hv;
  *(ushort4*)(aol + e) = lv;
}

// ---------------------------------------------------------------------------
extern "C" void kernel_launch(void* const* d_in, const int* in_sizes, int n_in,
                              void* d_out, int out_size, void* d_ws,
                              size_t ws_size, hipStream_t stream) {
  const float* x = (const float*)d_in[0];       // (B,N,C)
  const float* w_qkv = (const float*)d_in[1];   // (3C, C)
  const float* w_proj = (const float*)d_in[2];  // (C, C)
  const float* b_proj = (const float*)d_in[3];  // (C,)
  const float* paramR = (const float*)d_in[4];  // (1,)
  float* outp = (float*)d_out;                  // (B,N,C)

  const int nX = BB * NN * CC;  // 524288
  const int nWq = 3 * CC * CC;  // 786432
  const int nWp = CC * CC;      // 262144

  // ws layout: bf16 buffers first (8.4 MB, 16B-aligned), then fp32
  unsigned short* xh = (unsigned short*)d_ws;
  unsigned short* xl = xh + nX;
  unsigned short* wqh = xl + nX;
  unsigned short* wql = wqh + nWq;
  unsigned short* wph = wql + nWq;
  unsigned short* wpl = wph + nWp;
  unsigned short* aoh = wpl + nWp;
  unsigned short* aol = aoh + nX;
  float* qkv_ws = (float*)(aol + nX);   // 1024*1536 fp32
  float* num0 = qkv_ws + 1024 * 1536;   // 1024*512
  float* num1 = num0 + nX;              // 1024*512
  float* den0 = num1 + nX;              // 1024*8
  float* den1 = den0 + 1024 * HH;       // 1024*8

  // 1) hi/lo conversions (single fused launch)
  cvt_hilo3<<<1536, 256, 0, stream>>>(x, xh, xl, w_qkv, wqh, wql, w_proj, wph,
                                      wpl);

  // 2) qkv = x @ w_qkv^T : M=1024, N=1536, K=512 (384 blocks)
  gemm_mfma<false><<<dim3(3 * CC / 64, BB * NN / 64), 256, 0, stream>>>(
      xh, xl, wqh, wql, nullptr, qkv_ws, BB * NN, 3 * CC, CC);

  // 3) fused fourier attention, key-split 2-way -> partial num/den
  fourier_attn<<<dim3(HH * BB, (NN / 16) * 2), 512, 0, stream>>>(
      qkv_ws, paramR, num0, num1, den0, den1);

  // 4) combine + normalize -> hi/lo bf16 attention output
  combine_norm<<<nX / 1024, 256, 0, stream>>>(num0, num1, den0, den1, aoh,
                                              aol);

  // 5) out = attn @ w_proj^T + b_proj : M=1024, N=512, K=512 (128 blocks)
  gemm_mfma<true><<<dim3(CC / 64, BB * NN / 64), 256, 0, stream>>>(
      aoh, aol, wph, wpl, b_proj, outp, BB * NN, CC, CC);
}

// Round 7
// 128.539 us; speedup vs baseline: 2.2833x; 1.7942x over previous
//
#include <hip/hip_runtime.h>
#include <math.h>

// Problem constants: B=4, N=256, C=512, H=8, Dh=64
#define BB 4
#define NN 256
#define CC 512
#define HH 8
#define DH 64

typedef __attribute__((ext_vector_type(8))) short bf16x8;
typedef __attribute__((ext_vector_type(4))) float f32x4;
typedef __attribute__((ext_vector_type(2))) float f32x2;

__device__ inline unsigned short f2bf(float f) {
  unsigned u = __float_as_uint(f);
  u += 0x7FFFu + ((u >> 16) & 1u);  // round-to-nearest-even
  return (unsigned short)(u >> 16);
}
__device__ inline float bf2f(unsigned short s) {
  return __uint_as_float((unsigned)s << 16);
}

// ---------------------------------------------------------------------------
// Fused fp32 -> (hi, lo) bf16 split for all three inputs in ONE launch.
// Segments (blocks): x = 512, w_qkv = 768, w_proj = 256  -> grid 1536.
// ---------------------------------------------------------------------------
__global__ __launch_bounds__(256) void cvt_hilo3(
    const float* __restrict__ in0, unsigned short* __restrict__ h0,
    unsigned short* __restrict__ l0, const float* __restrict__ in1,
    unsigned short* __restrict__ h1, unsigned short* __restrict__ l1,
    const float* __restrict__ in2, unsigned short* __restrict__ h2,
    unsigned short* __restrict__ l2) {
  int b = blockIdx.x;
  const float* in;
  unsigned short *h, *l;
  if (b < 512) {
    in = in0; h = h0; l = l0;
  } else if (b < 1280) {
    in = in1; h = h1; l = l1; b -= 512;
  } else {
    in = in2; h = h2; l = l2; b -= 1280;
  }
  int i = (b * 256 + threadIdx.x) * 4;
  float4 f = *(const float4*)(in + i);
  float fa[4] = {f.x, f.y, f.z, f.w};
  ushort4 hv, lv;
  unsigned short* hp = (unsigned short*)&hv;
  unsigned short* lp = (unsigned short*)&lv;
#pragma unroll
  for (int j = 0; j < 4; j++) {
    unsigned short hb = f2bf(fa[j]);
    hp[j] = hb;
    lp[j] = f2bf(fa[j] - bf2f(hb));
  }
  *(ushort4*)(h + i) = hv;
  *(ushort4*)(l + i) = lv;
}

// ---------------------------------------------------------------------------
// MFMA GEMM, bf16 hi/lo split (3 products): C = A * B^T (+bias).
// r3-proven structure: LDS double-buffer, ONE barrier per K-step.
// 256 thr = 4 waves; tile 64x64; wave -> 32x32 (2x2 mfma 16x16x32). BK=64.
// LDS rows padded to 72 shorts (144B): b128 frags conflict-free. 72KB LDS.
// ---------------------------------------------------------------------------
template <bool BIAS>
__global__ __launch_bounds__(256, 2) void gemm_mfma(
    const unsigned short* __restrict__ Ah, const unsigned short* __restrict__ Al,
    const unsigned short* __restrict__ Bh, const unsigned short* __restrict__ Bl,
    const float* __restrict__ bias, float* __restrict__ C, int M, int N,
    int K) {
  __shared__ unsigned short sAh[2][64][72], sAl[2][64][72];
  __shared__ unsigned short sBh[2][64][72], sBl[2][64][72];
  const int t = threadIdx.x;
  const int lane = t & 63;
  const int w = t >> 6;
  const int bm = blockIdx.y * 64;
  const int bn = blockIdx.x * 64;
  const int wr = (w >> 1) * 32;  // wave row offset in tile
  const int wc = (w & 1) * 32;   // wave col offset
  const int quad = lane >> 4;
  const int l16 = lane & 15;

  // staging: 512 slots of 8 shorts per array
  const int r0 = t >> 3;       // 0..31
  const int r1 = r0 + 32;      // 32..63
  const int c8 = (t & 7) * 8;  // 0..56

  const size_t a0 = (size_t)(bm + r0) * K + c8;
  const size_t a1 = (size_t)(bm + r1) * K + c8;
  const size_t b0 = (size_t)(bn + r0) * K + c8;
  const size_t b1 = (size_t)(bn + r1) * K + c8;

  f32x4 acc[2][2];
#pragma unroll
  for (int i = 0; i < 2; i++)
#pragma unroll
    for (int j = 0; j < 2; j++) {
      acc[i][j][0] = 0.f;
      acc[i][j][1] = 0.f;
      acc[i][j][2] = 0.f;
      acc[i][j][3] = 0.f;
    }

  uint4 pa0, pa1, pa2, pa3, pb0, pb1, pb2, pb3;
#define GLOADS(K0)                       \
  pa0 = *(const uint4*)(Ah + a0 + (K0)); \
  pa1 = *(const uint4*)(Ah + a1 + (K0)); \
  pa2 = *(const uint4*)(Al + a0 + (K0)); \
  pa3 = *(const uint4*)(Al + a1 + (K0)); \
  pb0 = *(const uint4*)(Bh + b0 + (K0)); \
  pb1 = *(const uint4*)(Bh + b1 + (K0)); \
  pb2 = *(const uint4*)(Bl + b0 + (K0)); \
  pb3 = *(const uint4*)(Bl + b1 + (K0));

#define STORE(P)                  \
  *(uint4*)&sAh[P][r0][c8] = pa0; \
  *(uint4*)&sAh[P][r1][c8] = pa1; \
  *(uint4*)&sAl[P][r0][c8] = pa2; \
  *(uint4*)&sAl[P][r1][c8] = pa3; \
  *(uint4*)&sBh[P][r0][c8] = pb0; \
  *(uint4*)&sBh[P][r1][c8] = pb1; \
  *(uint4*)&sBl[P][r0][c8] = pb2; \
  *(uint4*)&sBl[P][r1][c8] = pb3;

  GLOADS(0)
  STORE(0)
  __syncthreads();
  GLOADS(64)

  int p = 0;
  for (int k0 = 0; k0 < K; k0 += 64) {
#pragma unroll
    for (int kk = 0; kk < 2; kk++) {
      const int kc = kk * 32 + quad * 8;
      bf16x8 ah[2], al[2], bh[2], bl[2];
#pragma unroll
      for (int i = 0; i < 2; i++) {
        ah[i] = *(const bf16x8*)&sAh[p][wr + i * 16 + l16][kc];
        al[i] = *(const bf16x8*)&sAl[p][wr + i * 16 + l16][kc];
        bh[i] = *(const bf16x8*)&sBh[p][wc + i * 16 + l16][kc];
        bl[i] = *(const bf16x8*)&sBl[p][wc + i * 16 + l16][kc];
      }
#pragma unroll
      for (int i = 0; i < 2; i++)
#pragma unroll
        for (int j = 0; j < 2; j++) {
          acc[i][j] = __builtin_amdgcn_mfma_f32_16x16x32_bf16(
              ah[i], bh[j], acc[i][j], 0, 0, 0);
          acc[i][j] = __builtin_amdgcn_mfma_f32_16x16x32_bf16(
              ah[i], bl[j], acc[i][j], 0, 0, 0);
          acc[i][j] = __builtin_amdgcn_mfma_f32_16x16x32_bf16(
              al[i], bh[j], acc[i][j], 0, 0, 0);
        }
    }
    if (k0 + 64 < K) {
      STORE(p ^ 1)
      if (k0 + 128 < K) {
        GLOADS(k0 + 128)
      }
    }
    __syncthreads();
    p ^= 1;
  }
#undef GLOADS
#undef STORE

  // epilogue: C/D layout col=lane&15, row=quad*4+reg (verified m89/m91)
#pragma unroll
  for (int i = 0; i < 2; i++)
#pragma unroll
    for (int j = 0; j < 2; j++) {
      int n = bn + wc + j * 16 + l16;
      float bv = BIAS ? bias[n] : 0.f;
#pragma unroll
      for (int r = 0; r < 4; r++) {
        int m = bm + wr + i * 16 + quad * 4 + r;
        C[(size_t)m * N + n] = acc[i][j][r] + bv;
      }
    }
}

// ---------------------------------------------------------------------------
// Fused Fourier attention v8 = v7 with the launch-bounds VGPR cap REMOVED.
// Spill forensics across rounds (VGPR_Count measured by rocprof):
//   (512,4) -> cap 64, used 40, healthy (r3, 42.7us)
//   (512,6) -> cap 40, SPILLS ~800B/thread -> 620MB HBM scratch (r6, 154us)
//   (512,8) -> cap 32, spills worse (r5, 208us)
// The cap arithmetic matches 512/(arg * 2 waves-per-SIMD-per-block): the
// min-occupancy arg is applied with blocks-per-CU-style math on this
// compiler, NOT waves/EU. Fix: plain __launch_bounds__(512) — compiler
// allocates ~56-72 VGPRs naturally; at <=64 that is 8 waves/SIMD = 4
// blocks/CU (LDS 30KB x 4 = 120KB fits), MORE than the forced target.
// Structure: grid (x = b*8+h [32], y = qc*2+kc [32]) = 1024 blocks; 8 waves.
// Each block: 16 queries x 128 keys, partial fp32 num/den; no V tile in LDS
// (V read from global/L2, XCD-local since dispatch id%8 = h).
// ---------------------------------------------------------------------------
__global__ __launch_bounds__(512) void fourier_attn(
    const float* __restrict__ qkv, const float* __restrict__ paramR,
    float* __restrict__ num0, float* __restrict__ num1,
    float* __restrict__ den0, float* __restrict__ den1) {
  __shared__ float Kt[64][68];            // K tile, row-major, padded
  __shared__ float Qs[16][64];            // staged queries (broadcast reads)
  __shared__ unsigned short Pah[16][72];  // a4 hi (bf16), padded 144B rows
  __shared__ unsigned short Pal[16][72];  // a4 lo
  __shared__ f32x4 Red[4][64];            // cross-wave partial sums

  const int t = threadIdx.x;
  const int lane = t & 63;
  const int wv = t >> 6;  // 0..7
  const int quad = lane >> 4;
  const int l16 = lane & 15;
  const int h = blockIdx.x & 7;
  const int b = blockIdx.x >> 3;
  const int qc = blockIdx.y >> 1;
  const int kc = blockIdx.y & 1;  // key half: tiles kc*2 .. kc*2+1
  const float R = paramR[0];
  const float cR = R * 0.15915494309189535f;  // R / (2*pi)

  const float* base = qkv + (size_t)b * NN * (3 * CC) + h * DH;

  if (t < 256) {
    int r = t >> 4;
    int c4 = (t & 15) << 2;
    *(float4*)&Qs[r][c4] =
        *(const float4*)(base + (size_t)(qc * 16 + r) * (3 * CC) + c4);
  }

  const int qi0 = wv * 2, qi1 = wv * 2 + 1;
  float Sp[2] = {0.f, 0.f};
  f32x4 oacc;
  oacc[0] = 0.f; oacc[1] = 0.f; oacc[2] = 0.f; oacc[3] = 0.f;

  // AV-phase role: dims chunk nc, key-half-within-tile g2
  const int nc = wv & 3;
  const int g2 = wv >> 2;
  const int kb = g2 * 32 + quad * 8;
  const int vcol = nc * 16 + l16;

  // K-tile prefetch regs (2 float4)
  float4 pk[2];
#define LOADK(JT)                                                          \
  _Pragma("unroll") for (int u0 = 0; u0 < 2; u0++) {                       \
    int u = t + 512 * u0;                                                  \
    int r_ = u >> 4;                                                       \
    int c4_ = (u & 15) << 2;                                               \
    pk[u0] =                                                               \
        *(const float4*)(base + (size_t)((JT) * 64 + r_) * (3 * CC) + CC + \
                         c4_);                                             \
  }

  LOADK(kc * 2)

  const f32x2 eps2 = {1e-30f, 1e-30f};
  const f32x2 cR2 = {cR, cR};

  for (int jj = 0; jj < 2; jj++) {
    const int jt = kc * 2 + jj;
    __syncthreads();  // B1: prev tile's score reads of Kt / AV reads of P done
#pragma unroll
    for (int u0 = 0; u0 < 2; u0++) {
      int u = t + 512 * u0;
      int r = u >> 4;          // key row
      int c4 = (u & 15) << 2;  // dim
      *(float4*)&Kt[r][c4] = pk[u0];
    }
    __syncthreads();  // B2: K tile (and Qs on jj=0) ready
    if (jj == 0) {
      LOADK(kc * 2 + 1)  // in flight across score below
    }

    // ---- score phase: lane = key, packed f32x2 math
    f32x2 nmA0 = {1.f, 1.f}, nmB0 = {1.f, 1.f};
    f32x2 nmA1 = {1.f, 1.f}, nmB1 = {1.f, 1.f};
    f32x2 dnA0 = {1.f, 1.f}, dnB0 = {1.f, 1.f};
    f32x2 dnA1 = {1.f, 1.f}, dnB1 = {1.f, 1.f};
#pragma unroll
    for (int d4 = 0; d4 < 16; d4++) {
      float4 k4 = *(const float4*)&Kt[lane][4 * d4];
      float4 qa = *(const float4*)&Qs[qi0][4 * d4];
      float4 qb = *(const float4*)&Qs[qi1][4 * d4];
      f32x2 kA = {k4.x, k4.y};
      f32x2 kB = {k4.z, k4.w};
      // (q - k) FIRST, then + eps: collision-safe (r2 NaN post-mortem)
      f32x2 dA0 = ((f32x2){qa.x, qa.y} - kA) + eps2;
      f32x2 dB0 = ((f32x2){qa.z, qa.w} - kB) + eps2;
      f32x2 dA1 = ((f32x2){qb.x, qb.y} - kA) + eps2;
      f32x2 dB1 = ((f32x2){qb.z, qb.w} - kB) + eps2;
      f32x2 gA0 = cR2 * dA0, gB0 = cR2 * dB0;
      f32x2 gA1 = cR2 * dA1, gB1 = cR2 * dB1;
      f32x2 sA0, sB0, sA1, sB1;
      sA0.x = __builtin_amdgcn_sinf(gA0.x);
      sA0.y = __builtin_amdgcn_sinf(gA0.y);
      sB0.x = __builtin_amdgcn_sinf(gB0.x);
      sB0.y = __builtin_amdgcn_sinf(gB0.y);
      sA1.x = __builtin_amdgcn_sinf(gA1.x);
      sA1.y = __builtin_amdgcn_sinf(gA1.y);
      sB1.x = __builtin_amdgcn_sinf(gB1.x);
      sB1.y = __builtin_amdgcn_sinf(gB1.y);
      nmA0 *= sA0;
      nmB0 *= sB0;
      nmA1 *= sA1;
      nmB1 *= sB1;
      dnA0 *= dA0;
      dnB0 *= dB0;
      dnA1 *= dA1;
      dnB1 *= dB1;
    }

    // ---- V prefetch from global (L2-hot; latency hides under P-write + B3)
    float vf[8];
#pragma unroll
    for (int j = 0; j < 8; j++) {
      vf[j] = base[(size_t)(jt * 64 + kb + j) * (3 * CC) + 2 * CC + vcol];
    }

    {
      f32x2 n0 = nmA0 * nmB0, d0 = dnA0 * dnB0;
      f32x2 n1 = nmA1 * nmB1, d1 = dnA1 * dnB1;
      float sc0 = (n0.x * n0.y) / (d0.x * d0.y);
      float sc1 = (n1.x * n1.y) / (d1.x * d1.y);
      float t0 = sc0 * sc0, t1 = sc1 * sc1;
      float a40 = t0 * t0, a41 = t1 * t1;
      Sp[0] += a40;
      Sp[1] += a41;
      unsigned short h0 = f2bf(a40), h1 = f2bf(a41);
      Pah[qi0][lane] = h0;
      Pal[qi0][lane] = f2bf(a40 - bf2f(h0));
      Pah[qi1][lane] = h1;
      Pal[qi1][lane] = f2bf(a41 - bf2f(h1));
    }
    __syncthreads();  // B3: P tile complete

    // ---- AV phase: one 16x16x32 MFMA triple per wave
    {
      bf16x8 pah = *(const bf16x8*)&Pah[l16][kb];
      bf16x8 pal = *(const bf16x8*)&Pal[l16][kb];
      bf16x8 vh, vl;
#pragma unroll
      for (int j = 0; j < 8; j++) {
        float f = vf[j];
        unsigned short hb = f2bf(f);
        vh[j] = (short)hb;
        vl[j] = (short)f2bf(f - bf2f(hb));
      }
      __builtin_amdgcn_s_setprio(1);
      oacc = __builtin_amdgcn_mfma_f32_16x16x32_bf16(pah, vh, oacc, 0, 0, 0);
      oacc = __builtin_amdgcn_mfma_f32_16x16x32_bf16(pah, vl, oacc, 0, 0, 0);
      oacc = __builtin_amdgcn_mfma_f32_16x16x32_bf16(pal, vh, oacc, 0, 0, 0);
      __builtin_amdgcn_s_setprio(0);
    }
  }
#undef LOADK

  // ---- finalize: write partial den (per query) + partial num (fp32)
  float* nump = kc ? num1 : num0;
  float* denp = kc ? den1 : den0;
#pragma unroll
  for (int q = 0; q < 2; q++) {
    float s = Sp[q];
#pragma unroll
    for (int off = 32; off > 0; off >>= 1) s += __shfl_xor(s, off, 64);
    if (lane == 0) {
      int m = b * NN + qc * 16 + qi0 + q;
      denp[(size_t)m * HH + h] = s;
    }
  }
  if (wv >= 4) Red[wv - 4][lane] = oacc;
  __syncthreads();
  if (wv < 4) {
    f32x4 part = Red[wv][lane];
#pragma unroll
    for (int r = 0; r < 4; r++) {
      int q = quad * 4 + r;
      int m = b * NN + qc * 16 + q;
      nump[(size_t)m * CC + h * DH + nc * 16 + l16] = oacc[r] + part[r];
    }
  }
}

// ---------------------------------------------------------------------------
// combine_norm: aoh/aol = hi/lo bf16 of (num0+num1)/(den0+den1+1e-6).
// 524288 elems, 4/thread -> 512 blocks x 256. ~6 MB traffic ~ 1.5 us.
// ---------------------------------------------------------------------------
__global__ __launch_bounds__(256) void combine_norm(
    const float* __restrict__ num0, const float* __restrict__ num1,
    const float* __restrict__ den0, const float* __restrict__ den1,
    unsigned short* __restrict__ aoh, unsigned short* __restrict__ aol) {
  int e = (blockIdx.x * 256 + threadIdx.x) * 4;
  int m = e >> 9;          // row (b*N+n)
  int hd = (e >> 6) & 7;   // head
  float den = den0[(size_t)m * HH + hd] + den1[(size_t)m * HH + hd] + 1e-6f;
  float4 n0 = *(const float4*)(num0 + e);
  float4 n1 = *(const float4*)(num1 + e);
  float o[4] = {(n0.x + n1.x) / den, (n0.y + n1.y) / den,
                (n0.z + n1.z) / den, (n0.w + n1.w) / den};
  ushort4 hv, lv;
  unsigned short* hp = (unsigned short*)&hv;
  unsigned short* lp = (unsigned short*)&lv;
#pragma unroll
  for (int j = 0; j < 4; j++) {
    unsigned short hb = f2bf(o[j]);
    hp[j] = hb;
    lp[j] = f2bf(o[j] - bf2f(hb));
  }
  *(ushort4*)(aoh + e) = hv;
  *(ushort4*)(aol + e) = lv;
}

// ---------------------------------------------------------------------------
extern "C" void kernel_launch(void* const* d_in, const int* in_sizes, int n_in,
                              void* d_out, int out_size, void* d_ws,
                              size_t ws_size, hipStream_t stream) {
  const float* x = (const float*)d_in[0];       // (B,N,C)
  const float* w_qkv = (const float*)d_in[1];   // (3C, C)
  const float* w_proj = (const float*)d_in[2];  // (C, C)
  const float* b_proj = (const float*)d_in[3];  // (C,)
  const float* paramR = (const float*)d_in[4];  // (1,)
  float* outp = (float*)d_out;                  // (B,N,C)

  const int nX = BB * NN * CC;  // 524288
  const int nWq = 3 * CC * CC;  // 786432
  const int nWp = CC * CC;      // 262144

  // ws layout: bf16 buffers first (8.4 MB, 16B-aligned), then fp32
  unsigned short* xh = (unsigned short*)d_ws;
  unsigned short* xl = xh + nX;
  unsigned short* wqh = xl + nX;
  unsigned short* wql = wqh + nWq;
  unsigned short* wph = wql + nWq;
  unsigned short* wpl = wph + nWp;
  unsigned short* aoh = wpl + nWp;
  unsigned short* aol = aoh + nX;
  float* qkv_ws = (float*)(aol + nX);   // 1024*1536 fp32
  float* num0 = qkv_ws + 1024 * 1536;   // 1024*512
  float* num1 = num0 + nX;              // 1024*512
  float* den0 = num1 + nX;              // 1024*8
  float* den1 = den0 + 1024 * HH;       // 1024*8

  // 1) hi/lo conversions (single fused launch)
  cvt_hilo3<<<1536, 256, 0, stream>>>(x, xh, xl, w_qkv, wqh, wql, w_proj, wph,
                                      wpl);

  // 2) qkv = x @ w_qkv^T : M=1024, N=1536, K=512 (384 blocks)
  gemm_mfma<false><<<dim3(3 * CC / 64, BB * NN / 64), 256, 0, stream>>>(
      xh, xl, wqh, wql, nullptr, qkv_ws, BB * NN, 3 * CC, CC);

  // 3) fused fourier attention, key-split 2-way -> partial num/den
  fourier_attn<<<dim3(HH * BB, (NN / 16) * 2), 512, 0, stream>>>(
      qkv_ws, paramR, num0, num1, den0, den1);

  // 4) combine + normalize -> hi/lo bf16 attention output
  combine_norm<<<nX / 1024, 256, 0, stream>>>(num0, num1, den0, den1, aoh,
                                              aol);

  // 5) out = attn @ w_proj^T + b_proj : M=1024, N=512, K=512 (128 blocks)
  gemm_mfma<true><<<dim3(CC / 64, BB * NN / 64), 256, 0, stream>>>(
      aoh, aol, wph, wpl, b_proj, outp, BB * NN, CC, CC);
}

// Round 8
// 124.241 us; speedup vs baseline: 2.3623x; 1.0346x over previous
//
#include <hip/hip_runtime.h>
#include <math.h>

// Problem constants: B=4, N=256, C=512, H=8, Dh=64
#define BB 4
#define NN 256
#define CC 512
#define HH 8
#define DH 64

typedef __attribute__((ext_vector_type(8))) short bf16x8;
typedef __attribute__((ext_vector_type(4))) float f32x4;
typedef __attribute__((ext_vector_type(2))) float f32x2;

__device__ inline unsigned short f2bf(float f) {
  unsigned u = __float_as_uint(f);
  u += 0x7FFFu + ((u >> 16) & 1u);  // round-to-nearest-even
  return (unsigned short)(u >> 16);
}
__device__ inline float bf2f(unsigned short s) {
  return __uint_as_float((unsigned)s << 16);
}

// ---------------------------------------------------------------------------
// Fused fp32 -> (hi, lo) bf16 split for all three inputs in ONE launch.
// Segments (blocks): x = 512, w_qkv = 768, w_proj = 256  -> grid 1536.
// ---------------------------------------------------------------------------
__global__ __launch_bounds__(256) void cvt_hilo3(
    const float* __restrict__ in0, unsigned short* __restrict__ h0,
    unsigned short* __restrict__ l0, const float* __restrict__ in1,
    unsigned short* __restrict__ h1, unsigned short* __restrict__ l1,
    const float* __restrict__ in2, unsigned short* __restrict__ h2,
    unsigned short* __restrict__ l2) {
  int b = blockIdx.x;
  const float* in;
  unsigned short *h, *l;
  if (b < 512) {
    in = in0; h = h0; l = l0;
  } else if (b < 1280) {
    in = in1; h = h1; l = l1; b -= 512;
  } else {
    in = in2; h = h2; l = l2; b -= 1280;
  }
  int i = (b * 256 + threadIdx.x) * 4;
  float4 f = *(const float4*)(in + i);
  float fa[4] = {f.x, f.y, f.z, f.w};
  ushort4 hv, lv;
  unsigned short* hp = (unsigned short*)&hv;
  unsigned short* lp = (unsigned short*)&lv;
#pragma unroll
  for (int j = 0; j < 4; j++) {
    unsigned short hb = f2bf(fa[j]);
    hp[j] = hb;
    lp[j] = f2bf(fa[j] - bf2f(hb));
  }
  *(ushort4*)(h + i) = hv;
  *(ushort4*)(l + i) = lv;
}

// ---------------------------------------------------------------------------
// MFMA GEMM, bf16 hi/lo split (3 products): C = A * B^T (+bias).
// r3-proven structure: LDS double-buffer, ONE barrier per K-step.
// 256 thr = 4 waves; tile 64x64; wave -> 32x32 (2x2 mfma 16x16x32). BK=64.
// LDS rows padded to 72 shorts (144B): b128 frags conflict-free. 72KB LDS.
// ---------------------------------------------------------------------------
template <bool BIAS>
__global__ __launch_bounds__(256, 2) void gemm_mfma(
    const unsigned short* __restrict__ Ah, const unsigned short* __restrict__ Al,
    const unsigned short* __restrict__ Bh, const unsigned short* __restrict__ Bl,
    const float* __restrict__ bias, float* __restrict__ C, int M, int N,
    int K) {
  __shared__ unsigned short sAh[2][64][72], sAl[2][64][72];
  __shared__ unsigned short sBh[2][64][72], sBl[2][64][72];
  const int t = threadIdx.x;
  const int lane = t & 63;
  const int w = t >> 6;
  const int bm = blockIdx.y * 64;
  const int bn = blockIdx.x * 64;
  const int wr = (w >> 1) * 32;  // wave row offset in tile
  const int wc = (w & 1) * 32;   // wave col offset
  const int quad = lane >> 4;
  const int l16 = lane & 15;

  // staging: 512 slots of 8 shorts per array
  const int r0 = t >> 3;       // 0..31
  const int r1 = r0 + 32;      // 32..63
  const int c8 = (t & 7) * 8;  // 0..56

  const size_t a0 = (size_t)(bm + r0) * K + c8;
  const size_t a1 = (size_t)(bm + r1) * K + c8;
  const size_t b0 = (size_t)(bn + r0) * K + c8;
  const size_t b1 = (size_t)(bn + r1) * K + c8;

  f32x4 acc[2][2];
#pragma unroll
  for (int i = 0; i < 2; i++)
#pragma unroll
    for (int j = 0; j < 2; j++) {
      acc[i][j][0] = 0.f;
      acc[i][j][1] = 0.f;
      acc[i][j][2] = 0.f;
      acc[i][j][3] = 0.f;
    }

  uint4 pa0, pa1, pa2, pa3, pb0, pb1, pb2, pb3;
#define GLOADS(K0)                       \
  pa0 = *(const uint4*)(Ah + a0 + (K0)); \
  pa1 = *(const uint4*)(Ah + a1 + (K0)); \
  pa2 = *(const uint4*)(Al + a0 + (K0)); \
  pa3 = *(const uint4*)(Al + a1 + (K0)); \
  pb0 = *(const uint4*)(Bh + b0 + (K0)); \
  pb1 = *(const uint4*)(Bh + b1 + (K0)); \
  pb2 = *(const uint4*)(Bl + b0 + (K0)); \
  pb3 = *(const uint4*)(Bl + b1 + (K0));

#define STORE(P)                  \
  *(uint4*)&sAh[P][r0][c8] = pa0; \
  *(uint4*)&sAh[P][r1][c8] = pa1; \
  *(uint4*)&sAl[P][r0][c8] = pa2; \
  *(uint4*)&sAl[P][r1][c8] = pa3; \
  *(uint4*)&sBh[P][r0][c8] = pb0; \
  *(uint4*)&sBh[P][r1][c8] = pb1; \
  *(uint4*)&sBl[P][r0][c8] = pb2; \
  *(uint4*)&sBl[P][r1][c8] = pb3;

  GLOADS(0)
  STORE(0)
  __syncthreads();
  GLOADS(64)

  int p = 0;
  for (int k0 = 0; k0 < K; k0 += 64) {
#pragma unroll
    for (int kk = 0; kk < 2; kk++) {
      const int kc = kk * 32 + quad * 8;
      bf16x8 ah[2], al[2], bh[2], bl[2];
#pragma unroll
      for (int i = 0; i < 2; i++) {
        ah[i] = *(const bf16x8*)&sAh[p][wr + i * 16 + l16][kc];
        al[i] = *(const bf16x8*)&sAl[p][wr + i * 16 + l16][kc];
        bh[i] = *(const bf16x8*)&sBh[p][wc + i * 16 + l16][kc];
        bl[i] = *(const bf16x8*)&sBl[p][wc + i * 16 + l16][kc];
      }
#pragma unroll
      for (int i = 0; i < 2; i++)
#pragma unroll
        for (int j = 0; j < 2; j++) {
          acc[i][j] = __builtin_amdgcn_mfma_f32_16x16x32_bf16(
              ah[i], bh[j], acc[i][j], 0, 0, 0);
          acc[i][j] = __builtin_amdgcn_mfma_f32_16x16x32_bf16(
              ah[i], bl[j], acc[i][j], 0, 0, 0);
          acc[i][j] = __builtin_amdgcn_mfma_f32_16x16x32_bf16(
              al[i], bh[j], acc[i][j], 0, 0, 0);
        }
    }
    if (k0 + 64 < K) {
      STORE(p ^ 1)
      if (k0 + 128 < K) {
        GLOADS(k0 + 128)
      }
    }
    __syncthreads();
    p ^= 1;
  }
#undef GLOADS
#undef STORE

  // epilogue: C/D layout col=lane&15, row=quad*4+reg (verified m89/m91)
#pragma unroll
  for (int i = 0; i < 2; i++)
#pragma unroll
    for (int j = 0; j < 2; j++) {
      int n = bn + wc + j * 16 + l16;
      float bv = BIAS ? bias[n] : 0.f;
#pragma unroll
      for (int r = 0; r < 4; r++) {
        int m = bm + wr + i * 16 + quad * 4 + r;
        C[(size_t)m * N + n] = acc[i][j][r] + bv;
      }
    }
}

// ---------------------------------------------------------------------------
// Fused Fourier attention v9: SMALL-BLOCK / LOW-CONVOY restructure.
// r7 forensics: spill fixed (VGPR 96, clean traffic) yet dur pinned at 44us
// == r3. Issue model says ~9us/SIMD floor -> latency/convoy-bound: 512-thr
// blocks at VGPR 96 = only 2 resident blocks/CU (16 waves), 6 barriers/pass.
// v9: 256 threads (4 waves), 8 queries/block (2/wave — per-wave score code
// UNCHANGED), 4-way key-split: block = one 64-key tile. 4096 blocks.
//  - 2 barriers/block (stage-done, P-ready); no prefetch state; no Red
//    (each wave does both key-halves = 6 MFMA into private oacc).
//  - expected VGPR ~80-88 -> 5-6 blocks/CU = 20-24 waves/CU resident.
//  - partial num/den now 4-way; combine_norm sums 4.
// XCD locality: linear id % 8 = blockIdx.x % 8 = h (K/V slab per (b,h) stays
// on one XCD's L2). Score math bit-identical to r3/r7 (collision-safe eps).
// NO launch_bounds min-arg (r5/r6 spill lesson).
// ---------------------------------------------------------------------------
__global__ __launch_bounds__(256) void fourier_attn(
    const float* __restrict__ qkv, const float* __restrict__ paramR,
    float* __restrict__ num0, float* __restrict__ num1,
    float* __restrict__ num2, float* __restrict__ num3,
    float* __restrict__ den0, float* __restrict__ den1,
    float* __restrict__ den2, float* __restrict__ den3) {
  __shared__ float Kt[64][68];            // K tile, row-major, padded
  __shared__ float Qs[8][64];             // 8 staged queries
  __shared__ unsigned short Pah[16][72];  // a4 hi (rows 8-15 zeroed)
  __shared__ unsigned short Pal[16][72];  // a4 lo

  const int t = threadIdx.x;
  const int lane = t & 63;
  const int wv = t >> 6;  // 0..3
  const int quad = lane >> 4;
  const int l16 = lane & 15;
  const int h = blockIdx.x & 7;
  const int b = blockIdx.x >> 3;
  const int qg = blockIdx.y >> 2;   // 0..31: 8-query group
  const int kc4 = blockIdx.y & 3;   // 0..3: 64-key tile
  const float R = paramR[0];
  const float cR = R * 0.15915494309189535f;  // R / (2*pi)

  const float* base = qkv + (size_t)b * NN * (3 * CC) + h * DH;
  const int jt64 = kc4 * 64;

  // ---- stage: K tile (4 slots/thread), 8 queries, zero P pad rows
  float4 pk[4];
#pragma unroll
  for (int s = 0; s < 4; s++) {
    int u = t + 256 * s;
    int r = u >> 4;
    int c4 = (u & 15) << 2;
    pk[s] = *(const float4*)(base + (size_t)(jt64 + r) * (3 * CC) + CC + c4);
  }
  if (t < 128) {
    int r = t >> 4;
    int c4 = (t & 15) << 2;
    *(float4*)&Qs[r][c4] =
        *(const float4*)(base + (size_t)(qg * 8 + r) * (3 * CC) + c4);
  }
  if (t < 288) {  // zero uints 288..575 = ushort rows 8..15
    ((unsigned*)Pah)[288 + t] = 0u;
    ((unsigned*)Pal)[288 + t] = 0u;
  }
#pragma unroll
  for (int s = 0; s < 4; s++) {
    int u = t + 256 * s;
    int r = u >> 4;
    int c4 = (u & 15) << 2;
    *(float4*)&Kt[r][c4] = pk[s];
  }
  __syncthreads();  // B1: Kt, Qs, P-pad ready

  const int qi0 = wv * 2, qi1 = wv * 2 + 1;  // this wave's 2 queries (0..7)
  const int nc = wv;                          // this wave's dim chunk
  const int vcol = nc * 16 + l16;

  // ---- score phase: lane = key, packed f32x2 math (identical to r3/r7)
  const f32x2 eps2 = {1e-30f, 1e-30f};
  const f32x2 cR2 = {cR, cR};
  f32x2 nmA0 = {1.f, 1.f}, nmB0 = {1.f, 1.f};
  f32x2 nmA1 = {1.f, 1.f}, nmB1 = {1.f, 1.f};
  f32x2 dnA0 = {1.f, 1.f}, dnB0 = {1.f, 1.f};
  f32x2 dnA1 = {1.f, 1.f}, dnB1 = {1.f, 1.f};
#pragma unroll
  for (int d4 = 0; d4 < 16; d4++) {
    float4 k4 = *(const float4*)&Kt[lane][4 * d4];
    float4 qa = *(const float4*)&Qs[qi0][4 * d4];
    float4 qb = *(const float4*)&Qs[qi1][4 * d4];
    f32x2 kA = {k4.x, k4.y};
    f32x2 kB = {k4.z, k4.w};
    // (q - k) FIRST, then + eps: collision-safe (r2 NaN post-mortem)
    f32x2 dA0 = ((f32x2){qa.x, qa.y} - kA) + eps2;
    f32x2 dB0 = ((f32x2){qa.z, qa.w} - kB) + eps2;
    f32x2 dA1 = ((f32x2){qb.x, qb.y} - kA) + eps2;
    f32x2 dB1 = ((f32x2){qb.z, qb.w} - kB) + eps2;
    f32x2 gA0 = cR2 * dA0, gB0 = cR2 * dB0;
    f32x2 gA1 = cR2 * dA1, gB1 = cR2 * dB1;
    f32x2 sA0, sB0, sA1, sB1;
    sA0.x = __builtin_amdgcn_sinf(gA0.x);
    sA0.y = __builtin_amdgcn_sinf(gA0.y);
    sB0.x = __builtin_amdgcn_sinf(gB0.x);
    sB0.y = __builtin_amdgcn_sinf(gB0.y);
    sA1.x = __builtin_amdgcn_sinf(gA1.x);
    sA1.y = __builtin_amdgcn_sinf(gA1.y);
    sB1.x = __builtin_amdgcn_sinf(gB1.x);
    sB1.y = __builtin_amdgcn_sinf(gB1.y);
    nmA0 *= sA0;
    nmB0 *= sB0;
    nmA1 *= sA1;
    nmB1 *= sB1;
    dnA0 *= dA0;
    dnB0 *= dB0;
    dnA1 *= dA1;
    dnB1 *= dB1;
  }

  // ---- V loads for both key-halves (L2-hot; hidden under finalize + B2)
  float vfa[8], vfb[8];
#pragma unroll
  for (int j = 0; j < 8; j++) {
    vfa[j] = base[(size_t)(jt64 + quad * 8 + j) * (3 * CC) + 2 * CC + vcol];
    vfb[j] =
        base[(size_t)(jt64 + 32 + quad * 8 + j) * (3 * CC) + 2 * CC + vcol];
  }

  // ---- finalize scores -> a4, per-query partial denominators
  float Sp[2];
  {
    f32x2 n0 = nmA0 * nmB0, d0 = dnA0 * dnB0;
    f32x2 n1 = nmA1 * nmB1, d1 = dnA1 * dnB1;
    float sc0 = (n0.x * n0.y) / (d0.x * d0.y);
    float sc1 = (n1.x * n1.y) / (d1.x * d1.y);
    float t0 = sc0 * sc0, t1 = sc1 * sc1;
    float a40 = t0 * t0, a41 = t1 * t1;
    Sp[0] = a40;
    Sp[1] = a41;
    unsigned short h0 = f2bf(a40), h1 = f2bf(a41);
    Pah[qi0][lane] = h0;
    Pal[qi0][lane] = f2bf(a40 - bf2f(h0));
    Pah[qi1][lane] = h1;
    Pal[qi1][lane] = f2bf(a41 - bf2f(h1));
  }
  __syncthreads();  // B2: P tile complete

  // ---- AV phase: both key-halves, 6 MFMA into private oacc
  f32x4 oacc;
  oacc[0] = 0.f; oacc[1] = 0.f; oacc[2] = 0.f; oacc[3] = 0.f;
  {
    bf16x8 pah0 = *(const bf16x8*)&Pah[l16][quad * 8];
    bf16x8 pal0 = *(const bf16x8*)&Pal[l16][quad * 8];
    bf16x8 pah1 = *(const bf16x8*)&Pah[l16][32 + quad * 8];
    bf16x8 pal1 = *(const bf16x8*)&Pal[l16][32 + quad * 8];
    bf16x8 vh0, vl0, vh1, vl1;
#pragma unroll
    for (int j = 0; j < 8; j++) {
      unsigned short hb;
      hb = f2bf(vfa[j]);
      vh0[j] = (short)hb;
      vl0[j] = (short)f2bf(vfa[j] - bf2f(hb));
      hb = f2bf(vfb[j]);
      vh1[j] = (short)hb;
      vl1[j] = (short)f2bf(vfb[j] - bf2f(hb));
    }
    __builtin_amdgcn_s_setprio(1);
    oacc = __builtin_amdgcn_mfma_f32_16x16x32_bf16(pah0, vh0, oacc, 0, 0, 0);
    oacc = __builtin_amdgcn_mfma_f32_16x16x32_bf16(pah0, vl0, oacc, 0, 0, 0);
    oacc = __builtin_amdgcn_mfma_f32_16x16x32_bf16(pal0, vh0, oacc, 0, 0, 0);
    oacc = __builtin_amdgcn_mfma_f32_16x16x32_bf16(pah1, vh1, oacc, 0, 0, 0);
    oacc = __builtin_amdgcn_mfma_f32_16x16x32_bf16(pah1, vl1, oacc, 0, 0, 0);
    oacc = __builtin_amdgcn_mfma_f32_16x16x32_bf16(pal1, vh1, oacc, 0, 0, 0);
    __builtin_amdgcn_s_setprio(0);
  }

  // ---- write partial den (per query) + partial num (fp32)
  float* nump = (kc4 == 0) ? num0 : (kc4 == 1) ? num1 : (kc4 == 2) ? num2
                                                                   : num3;
  float* denp = (kc4 == 0) ? den0 : (kc4 == 1) ? den1 : (kc4 == 2) ? den2
                                                                   : den3;
#pragma unroll
  for (int q = 0; q < 2; q++) {
    float s = Sp[q];
#pragma unroll
    for (int off = 32; off > 0; off >>= 1) s += __shfl_xor(s, off, 64);
    if (lane == 0) {
      int m = b * NN + qg * 8 + qi0 + q;
      denp[(size_t)m * HH + h] = s;
    }
  }
#pragma unroll
  for (int r = 0; r < 4; r++) {
    int q = quad * 4 + r;  // 0..15; valid queries are 0..7
    if (q < 8) {
      int m = b * NN + qg * 8 + q;
      nump[(size_t)m * CC + h * DH + nc * 16 + l16] = oacc[r];
    }
  }
}

// ---------------------------------------------------------------------------
// combine_norm: aoh/aol = hi/lo bf16 of (Σ num_i)/(Σ den_i + 1e-6).
// 524288 elems, 4/thread -> 512 blocks x 256.
// ---------------------------------------------------------------------------
__global__ __launch_bounds__(256) void combine_norm(
    const float* __restrict__ num0, const float* __restrict__ num1,
    const float* __restrict__ num2, const float* __restrict__ num3,
    const float* __restrict__ den0, const float* __restrict__ den1,
    const float* __restrict__ den2, const float* __restrict__ den3,
    unsigned short* __restrict__ aoh, unsigned short* __restrict__ aol) {
  int e = (blockIdx.x * 256 + threadIdx.x) * 4;
  int m = e >> 9;         // row (b*N+n)
  int hd = (e >> 6) & 7;  // head
  size_t di = (size_t)m * HH + hd;
  float den = ((den0[di] + den1[di]) + (den2[di] + den3[di])) + 1e-6f;
  float4 n0 = *(const float4*)(num0 + e);
  float4 n1 = *(const float4*)(num1 + e);
  float4 n2 = *(const float4*)(num2 + e);
  float4 n3 = *(const float4*)(num3 + e);
  float o[4] = {((n0.x + n1.x) + (n2.x + n3.x)) / den,
                ((n0.y + n1.y) + (n2.y + n3.y)) / den,
                ((n0.z + n1.z) + (n2.z + n3.z)) / den,
                ((n0.w + n1.w) + (n2.w + n3.w)) / den};
  ushort4 hv, lv;
  unsigned short* hp = (unsigned short*)&hv;
  unsigned short* lp = (unsigned short*)&lv;
#pragma unroll
  for (int j = 0; j < 4; j++) {
    unsigned short hb = f2bf(o[j]);
    hp[j] = hb;
    lp[j] = f2bf(o[j] - bf2f(hb));
  }
  *(ushort4*)(aoh + e) = hv;
  *(ushort4*)(aol + e) = lv;
}

// ---------------------------------------------------------------------------
extern "C" void kernel_launch(void* const* d_in, const int* in_sizes, int n_in,
                              void* d_out, int out_size, void* d_ws,
                              size_t ws_size, hipStream_t stream) {
  const float* x = (const float*)d_in[0];       // (B,N,C)
  const float* w_qkv = (const float*)d_in[1];   // (3C, C)
  const float* w_proj = (const float*)d_in[2];  // (C, C)
  const float* b_proj = (const float*)d_in[3];  // (C,)
  const float* paramR = (const float*)d_in[4];  // (1,)
  float* outp = (float*)d_out;                  // (B,N,C)

  const int nX = BB * NN * CC;  // 524288
  const int nWq = 3 * CC * CC;  // 786432
  const int nWp = CC * CC;      // 262144

  // ws layout: bf16 buffers first (8.4 MB, 16B-aligned), then fp32
  unsigned short* xh = (unsigned short*)d_ws;
  unsigned short* xl = xh + nX;
  unsigned short* wqh = xl + nX;
  unsigned short* wql = wqh + nWq;
  unsigned short* wph = wql + nWq;
  unsigned short* wpl = wph + nWp;
  unsigned short* aoh = wpl + nWp;
  unsigned short* aol = aoh + nX;
  float* qkv_ws = (float*)(aol + nX);  // 1024*1536 fp32
  float* num0 = qkv_ws + 1024 * 1536;  // 4x 1024*512
  float* num1 = num0 + nX;
  float* num2 = num1 + nX;
  float* num3 = num2 + nX;
  float* den0 = num3 + nX;  // 4x 1024*8
  float* den1 = den0 + 1024 * HH;
  float* den2 = den1 + 1024 * HH;
  float* den3 = den2 + 1024 * HH;

  // 1) hi/lo conversions (single fused launch)
  cvt_hilo3<<<1536, 256, 0, stream>>>(x, xh, xl, w_qkv, wqh, wql, w_proj, wph,
                                      wpl);

  // 2) qkv = x @ w_qkv^T : M=1024, N=1536, K=512 (384 blocks)
  gemm_mfma<false><<<dim3(3 * CC / 64, BB * NN / 64), 256, 0, stream>>>(
      xh, xl, wqh, wql, nullptr, qkv_ws, BB * NN, 3 * CC, CC);

  // 3) fused fourier attention, key-split 4-way, 256-thread blocks
  //    grid (x = b*8+h [32], y = qg*4+kc4 [128]) = 4096 blocks
  fourier_attn<<<dim3(HH * BB, (NN / 8) * 4), 256, 0, stream>>>(
      qkv_ws, paramR, num0, num1, num2, num3, den0, den1, den2, den3);

  // 4) combine + normalize -> hi/lo bf16 attention output
  combine_norm<<<nX / 1024, 256, 0, stream>>>(num0, num1, num2, num3, den0,
                                              den1, den2, den3, aoh, aol);

  // 5) out = attn @ w_proj^T + b_proj : M=1024, N=512, K=512 (128 blocks)
  gemm_mfma<true><<<dim3(CC / 64, BB * NN / 64), 256, 0, stream>>>(
      aoh, aol, wph, wpl, b_proj, outp, BB * NN, CC, CC);
}